// Round 4
// baseline (35.406 us; speedup 1.0000x reference)
//
#include <hip/hip_runtime.h>

typedef float  f32x4  __attribute__((ext_vector_type(4)));
typedef float  f32x16 __attribute__((ext_vector_type(16)));
typedef short  s16x8  __attribute__((ext_vector_type(8)));
typedef _Float16 h2 __attribute__((ext_vector_type(2)));
typedef unsigned short u16;
typedef u16 u16x4 __attribute__((ext_vector_type(4)));

#define N_DIMS 1024
#define N_OSC  352
#define BATCH  4096
#define EPSV   1e-6f
#define INV2PI 0.15915494309189535f

// ---------------- conversion f32 -> bf16 ----------------
__device__ __forceinline__ u16 f2bf(float f){
  unsigned u = __builtin_bit_cast(unsigned, f);
  u += 0x7FFFu + ((u >> 16) & 1u);   // round-to-nearest-even
  return (u16)(u >> 16);
}

#define NX4 1048576   // 4096*1024/4
#define NW4 90112     // 352*1024/4 (per weight matrix)
// wb is padded to 768 rows: [Wp(352); Wa(352); zeros(64)]

__global__ __launch_bounds__(256) void convert_k(const f32x4* __restrict__ x,
    const f32x4* __restrict__ wp, const f32x4* __restrict__ wa,
    u16x4* __restrict__ xb, u16x4* __restrict__ wb){
  int i = blockIdx.x * 256 + threadIdx.x;
  f32x4 v; u16x4* dst;
  if (i < NX4) { v = x[i]; dst = xb + i; }
  else {
    int j = i - NX4;
    dst = wb + j;
    if (j < NW4)        v = wp[j];
    else if (j < 2*NW4) v = wa[j - NW4];
    else { u16x4 z = {0,0,0,0}; *dst = z; return; }
  }
  u16x4 r;
  r[0]=f2bf(v[0]); r[1]=f2bf(v[1]); r[2]=f2bf(v[2]); r[3]=f2bf(v[3]);
  *dst = r;
}

// ---------------- GEMM: C[4096][768] = x @ [Wp;Wa;0]^T ----------------
// BM=64, BN=128, BK=64. 4 waves (2x2); wave tile 32x64 via 32x32x16 MFMA, acc[2].
// LDS/buf: A 64x64 bf16 (8 KB) + B 128x64 (16 KB); double-buffered 48 KB.
// T2 swizzle on 128B rows (8x16B slots): slot q stored at q ^ (row&7); staged via
// inverse-swizzled GLOBAL source + linear LDS dest (rule #21), read swizzled.
__device__ __forceinline__ void gload16(const u16* g, u16* l){
  __builtin_amdgcn_global_load_lds(
      (const __attribute__((address_space(1))) unsigned int*)(g),
      (__attribute__((address_space(3))) unsigned int*)(l), 16, 0, 0);
}

__global__ __launch_bounds__(256) void gemm_k(const u16* __restrict__ xb,
    const u16* __restrict__ wb, float* __restrict__ phase0, float* __restrict__ amp0){
  __shared__ u16 lds[2][12288];         // [buf][24 KB]: A at 0 (4096 u16), B at 4096
  const int tid = threadIdx.x;
  const int l   = tid & 63;
  const int w   = tid >> 6;
  const int m0  = blockIdx.y * 64;
  const int n0  = blockIdx.x * 128;

  // staging: each wave-issue covers 8 rows x 128 B; source k-col inverse-swizzled
  const int sr8  = l >> 3;                        // row&7 within any 8-row group
  const int scol = (((l & 7) ^ sr8) * 8);         // u16 units
  const u16* ga = xb + (size_t)(m0 + w*16 + sr8) * N_DIMS + scol;   // 2 issues, +8 rows
  const u16* gb = wb + (size_t)(n0 + w*32 + sr8) * N_DIMS + scol;   // 4 issues, +8 rows

  #define STAGE(b, kt) { \
    const u16* gA = ga + (kt)*64; \
    const u16* gB = gb + (kt)*64; \
    gload16(gA,             &lds[b][w*1024]); \
    gload16(gA + 8*N_DIMS,  &lds[b][w*1024 + 512]); \
    gload16(gB,             &lds[b][4096 + w*2048]); \
    gload16(gB + 8*N_DIMS,  &lds[b][4096 + w*2048 + 512]); \
    gload16(gB + 16*N_DIMS, &lds[b][4096 + w*2048 + 1024]); \
    gload16(gB + 24*N_DIMS, &lds[b][4096 + w*2048 + 1536]); }

  const int r31 = l & 31;
  const int kh  = l >> 5;                // k-half: owns k 8*kh..8*kh+7 within k16
  const int wr = w >> 1, wc = w & 1;
  const int row_a = wr*32 + r31;
  const int base_a = row_a*64;
  const int sxa = row_a & 7;

  f32x16 acc[2] = {};
  STAGE(0, 0)
  __syncthreads();

  for (int kt = 0; kt < 16; kt++){
    const int cb = kt & 1;
    if (kt < 15) STAGE(cb^1, kt+1)
    #pragma unroll
    for (int ks = 0; ks < 4; ks++){
      const int s = ks*2 + kh;
      s16x8 a = *(const s16x8*)&lds[cb][base_a + ((s ^ sxa) * 8)];
      #pragma unroll
      for (int nf = 0; nf < 2; nf++){
        const int row_b = wc*64 + nf*32 + r31;
        s16x8 b = *(const s16x8*)&lds[cb][4096 + row_b*64 + ((s ^ (row_b & 7)) * 8)];
        acc[nf] = __builtin_amdgcn_mfma_f32_32x32x16_bf16(a, b, acc[nf], 0,0,0);
      }
    }
    __syncthreads();
  }
  #undef STAGE

  // C/D layout (m74/m101): col = l&31, row = (reg&3) + 8*(reg>>2) + 4*(l>>5)
  #pragma unroll
  for (int nf = 0; nf < 2; nf++){
    const int nb = n0 + wc*64 + nf*32;        // 32-col span, uniform class
    if (nb >= 2*N_OSC) continue;              // padding columns
    const bool isph = nb < N_OSC;
    float* __restrict__ op = isph ? phase0 : amp0;
    const int n = (isph ? nb : nb - N_OSC) + r31;
    #pragma unroll
    for (int r = 0; r < 16; r++){
      const int m = m0 + wr*32 + (r&3) + 8*(r>>2) + 4*kh;
      float v = acc[nf][r];
      float res;
      if (isph) { float t = v * INV2PI; res = t - floorf(t); }
      else      { res = fmaxf(fabsf(v), EPSV); }
      op[(size_t)m * N_OSC + n] = res;
    }
  }
}

// ---------------- iteration kernel: packed-f16 rotation, DPP-only reduce ----------------
__device__ __forceinline__ int ibc(h2 v){ return __builtin_bit_cast(int, v); }
__device__ __forceinline__ h2  hbc(int v){ return __builtin_bit_cast(h2, v); }

__device__ __forceinline__ h2 rowsum16(h2 x){
  int v = ibc(x);
  v = ibc(hbc(v) + hbc(__builtin_amdgcn_mov_dpp(v, 0x121, 0xF, 0xF, true))); // row_ror:1
  v = ibc(hbc(v) + hbc(__builtin_amdgcn_mov_dpp(v, 0x122, 0xF, 0xF, true))); // row_ror:2
  v = ibc(hbc(v) + hbc(__builtin_amdgcn_mov_dpp(v, 0x124, 0xF, 0xF, true))); // row_ror:4
  v = ibc(hbc(v) + hbc(__builtin_amdgcn_mov_dpp(v, 0x128, 0xF, 0xF, true))); // row_ror:8
  return hbc(v);
}

__device__ __forceinline__ void updp(h2& s, h2& c, h2 cA, h2 sA, h2 GS, h2 GC){
  h2 e  = c*GS - s*GC;        // eps (radians), |e| <= 0.02
  h2 s1 = s*cA + c*sA;
  h2 c1 = c*cA - s*sA;
  s = s1 + c1*e;
  c = c1 - s1*e;
}

__device__ __forceinline__ h2 splat2(_Float16 v){ h2 r; r[0]=v; r[1]=v; return r; }

__global__ __launch_bounds__(256) void iter_k(const float* __restrict__ phase0,
                                              float* __restrict__ amp){
  const int tid = threadIdx.x;
  const int l   = tid & 63;
  const int g   = l & 15;
  const int row = blockIdx.x*16 + (tid>>6)*4 + (l>>4);
  const size_t rb = (size_t)row * N_OSC;

  const h2 cAd = splat2((_Float16)0.99211470f), sAd = splat2((_Float16)0.12533323f);
  const h2 cAt = splat2((_Float16)0.92977649f), sAt = splat2((_Float16)0.36812455f);
  const h2 cAg = splat2((_Float16)-0.80901699f), sAg = splat2((_Float16)0.58778525f);
  const h2 kd = splat2((_Float16)6.25e-4f);    // DT*COUPLING/32
  const h2 kt = splat2((_Float16)3.125e-4f);   // /64
  const h2 kg = splat2((_Float16)7.8125e-5f);  // /256

  h2 sD, cD, sT[2], cT[2], sG[8], cG[8];
  {
    const float* pr = phase0 + rb;
    #define SCP(dstS, dstC, idx, p0, p1) { \
      float a0 = (p0), a1 = (p1); \
      dstS[idx][0] = (_Float16)__builtin_amdgcn_sinf(a0); \
      dstS[idx][1] = (_Float16)__builtin_amdgcn_sinf(a1); \
      dstC[idx][0] = (_Float16)__builtin_amdgcn_cosf(a0); \
      dstC[idx][1] = (_Float16)__builtin_amdgcn_cosf(a1); }
    {
      float2 d = *(const float2*)(pr + 2*g);
      sD[0] = (_Float16)__builtin_amdgcn_sinf(d.x);
      sD[1] = (_Float16)__builtin_amdgcn_sinf(d.y);
      cD[0] = (_Float16)__builtin_amdgcn_cosf(d.x);
      cD[1] = (_Float16)__builtin_amdgcn_cosf(d.y);
    }
    {
      float4 t = *(const float4*)(pr + 32 + 4*g);
      SCP(sT, cT, 0, t.x, t.y) SCP(sT, cT, 1, t.z, t.w)
    }
    #pragma unroll
    for (int i = 0; i < 4; i++){
      float4 v = *(const float4*)(pr + 96 + 16*g + 4*i);
      SCP(sG, cG, 2*i,   v.x, v.y) SCP(sG, cG, 2*i+1, v.z, v.w)
    }
    #undef SCP
  }

  h2 PD, PT, PG;
  #define REDUCE { \
    h2 pd; pd[0] = sD[0]+sD[1]; pd[1] = cD[0]+cD[1]; \
    h2 ts = sT[0]+sT[1], tc = cT[0]+cT[1]; \
    h2 pt; pt[0] = ts[0]+ts[1]; pt[1] = tc[0]+tc[1]; \
    h2 gs = ((sG[0]+sG[1])+(sG[2]+sG[3]))+((sG[4]+sG[5])+(sG[6]+sG[7])); \
    h2 gc = ((cG[0]+cG[1])+(cG[2]+cG[3]))+((cG[4]+cG[5])+(cG[6]+cG[7])); \
    h2 pg; pg[0] = gs[0]+gs[1]; pg[1] = gc[0]+gc[1]; \
    PD = rowsum16(pd); PT = rowsum16(pt); PG = rowsum16(pg); }

  REDUCE

  float Pth = 1.f, Pga = 1.f, mPth = 1.f, mPga = 1.f;
  for (int t = 0; t < 32; t++){
    h2 gd = PD * kd, gt = PT * kt, gg = PG * kg;   // (k*S, k*C)
    h2 GSd = splat2(gd[0]), GCd = splat2(gd[1]);
    h2 GSt = splat2(gt[0]), GCt = splat2(gt[1]);
    h2 GSg = splat2(gg[0]), GCg = splat2(gg[1]);
    updp(sD, cD, cAd, sAd, GSd, GCd);
    updp(sT[0], cT[0], cAt, sAt, GSt, GCt);
    updp(sT[1], cT[1], cAt, sAt, GSt, GCt);
    #pragma unroll
    for (int i = 0; i < 8; i++) updp(sG[i], cG[i], cAg, sAg, GSg, GCg);
    REDUCE
    float Sd = (float)PD[0], Cd = (float)PD[1];
    float St = (float)PT[0], Ct = (float)PT[1];
    float ft = 1.f + 0.003f * Cd * __builtin_amdgcn_rsqf(Cd*Cd + Sd*Sd);
    float fg = 1.f + 0.003f * Ct * __builtin_amdgcn_rsqf(Ct*Ct + St*St);
    Pth *= ft; mPth = fminf(mPth, Pth);
    Pga *= fg; mPga = fminf(mPga, Pga);
  }
  #undef REDUCE

  const float cth = EPSV * Pth / mPth;
  const float cga = EPSV * Pga / mPga;
  {
    float4 a = *(const float4*)(amp + rb + 32 + 4*g);
    a.x = fmaxf(a.x*Pth, cth); a.y = fmaxf(a.y*Pth, cth);
    a.z = fmaxf(a.z*Pth, cth); a.w = fmaxf(a.w*Pth, cth);
    *(float4*)(amp + rb + 32 + 4*g) = a;
  }
  #pragma unroll
  for (int i = 0; i < 4; i++){
    float4 a = *(const float4*)(amp + rb + 96 + 16*g + 4*i);
    a.x = fmaxf(a.x*Pga, cga); a.y = fmaxf(a.y*Pga, cga);
    a.z = fmaxf(a.z*Pga, cga); a.w = fmaxf(a.w*Pga, cga);
    *(float4*)(amp + rb + 96 + 16*g + 4*i) = a;
  }
}

// ---------------- launch ----------------
extern "C" void kernel_launch(void* const* d_in, const int* in_sizes, int n_in,
                              void* d_out, int out_size, void* d_ws, size_t ws_size,
                              hipStream_t stream){
  const float* x  = (const float*)d_in[0];
  const float* wp = (const float*)d_in[1];
  const float* wa = (const float*)d_in[2];
  float* out = (float*)d_out;
  char* ws = (char*)d_ws;
  u16* xb  = (u16*)(ws);                     // 8,388,608 B
  u16* wb  = (u16*)(ws + 8388608);           // 1,572,864 B (768 rows)
  float* phase0 = (float*)(ws + 9961472);    // 5,767,168 B

  convert_k<<<4864, 256, 0, stream>>>((const f32x4*)x, (const f32x4*)wp, (const f32x4*)wa,
                                      (u16x4*)xb, (u16x4*)wb);
  gemm_k<<<dim3(6, 64), 256, 0, stream>>>(xb, wb, phase0, out);
  iter_k<<<256, 256, 0, stream>>>(phase0, out);
}